// Round 9
// baseline (200.173 us; speedup 1.0000x reference)
//
#include <hip/hip_runtime.h>
#include <hip/hip_bf16.h>

typedef __attribute__((ext_vector_type(4))) float f32x4;
typedef __attribute__((ext_vector_type(4))) unsigned int u32x4;
typedef __attribute__((ext_vector_type(8))) short s16x8;

#define B_  128
#define P_  196
#define E_  2048
#define D_  512
#define A_  512
#define M_  (B_*P_)   // 25088

// global_load_lds: 16B per lane, dest = wave-uniform base + lane*16
typedef __attribute__((address_space(1))) const unsigned int gu32;
typedef __attribute__((address_space(3))) unsigned int lu32;
__device__ __forceinline__ void gl_lds16(const void* g, void* l) {
  __builtin_amdgcn_global_load_lds((gu32*)g, (lu32*)l, 16, 0, 0);
}

#define WAIT_VM4()  asm volatile("s_waitcnt vmcnt(4)"  ::: "memory")
#define WAIT_VM8()  asm volatile("s_waitcnt vmcnt(8)"  ::: "memory")
#define WAIT_VM12() asm volatile("s_waitcnt vmcnt(12)" ::: "memory")
#define WAIT_LGKM0() asm volatile("s_waitcnt lgkmcnt(0)" ::: "memory")

// ---------------------------------------------------------------------------
// Kernel W: transpose + rne-bf16 + PRE-SWIZZLED TILED store (R6 layout):
// WeTs[kt*16384 + ((a*32 + c8*8) ^ ((a&7)<<3)) + j] == exact 32KB LDS image
// of K-tile kt (a = n-row 0..511, c8 = (e&31)>>3, j = e&7).
// ---------------------------------------------------------------------------
__global__ void we_conv_kernel(const float* __restrict__ We,
                               unsigned short* __restrict__ WeTs) {
  __shared__ float tile[32][33];
  const int tx = threadIdx.x, ty = threadIdx.y;
  const int a0 = blockIdx.x * 32, e0 = blockIdx.y * 32;
  tile[ty][tx] = We[(e0 + ty) * A_ + a0 + tx];
  __syncthreads();
  const float v = tile[tx][ty];              // = We[e0+tx][a0+ty]
  const unsigned int u = __float_as_uint(v);
  const unsigned short r = (unsigned short)((u + 0x7fffu + ((u >> 16) & 1u)) >> 16);
  const int a = a0 + ty;                     // n-row 0..511
  const int kt = blockIdx.y;                 // e-tile
  const int c8 = tx >> 3, j = tx & 7;
  const int dest = ((a * 32 + c8 * 8) ^ ((a & 7) << 3)) + j;
  WeTs[kt * 16384 + dest] = r;
}

// ---------------------------------------------------------------------------
// Kernel A: att2pb[b][a] = decoder_hidden[b] @ Wd + bd[a] + be[a]  (fp32)
// ---------------------------------------------------------------------------
__global__ void att2_kernel(const float* __restrict__ h, const float* __restrict__ Wd,
                            const float* __restrict__ bd, const float* __restrict__ be,
                            float* __restrict__ att2pb) {
  const int b = blockIdx.x;
  const int t = threadIdx.x;  // 256
  __shared__ float hs[D_];
  hs[t] = h[b * D_ + t];
  hs[t + 256] = h[b * D_ + t + 256];
  __syncthreads();
  float a0 = 0.f, a1 = 0.f;
  for (int d = 0; d < D_; ++d) {
    const float hv = hs[d];
    a0 = fmaf(hv, Wd[d * A_ + t], a0);
    a1 = fmaf(hv, Wd[d * A_ + t + 256], a1);
  }
  att2pb[b * A_ + t] = a0 + bd[t] + be[t];
  att2pb[b * A_ + t + 256] = a1 + bd[t + 256] + be[t + 256];
}

// ---------------------------------------------------------------------------
__device__ inline unsigned pk2(float a, float b) {
  union { __hip_bfloat162 h; unsigned u; } cv;
  cv.h = __float22bfloat162_rn(make_float2(a, b));
  return cv.u;
}
__device__ inline s16x8 cvt8s(const f32x4 lo, const f32x4 hi) {
  union { u32x4 u; s16x8 s; } c;
  c.u[0] = pk2(lo[0], lo[1]);
  c.u[1] = pk2(lo[2], lo[3]);
  c.u[2] = pk2(hi[0], hi[1]);
  c.u[3] = pk2(hi[2], hi[3]);
  return c.s;
}

// ---------------------------------------------------------------------------
// Kernel B v8: 128m x 512n strip, 8 waves (2m x 4n, wave tile 64x128), K=32.
// A: DIRECT global->reg in fragment layout (L1 serves the 4-way n-wave reuse),
//    cvt in-register, NO LDS for A.
// B: LDS via global_load_lds DMA (pre-swizzled 32KB images), TRIPLE-buffered,
//    prefetch depth 2, counted vmcnt + raw s_barrier (R6-proven discipline).
// Per iter: cvt A(t) -> issue A(t+1) 8 loads + B(t+2) 4 DMAs -> read B frags
// -> 32 MFMA -> vmcnt(12) [retires B(t+1)] -> lgkm(0) -> barrier.
// ---------------------------------------------------------------------------
__launch_bounds__(512, 2)
__global__ void score_kernel(const float* __restrict__ enc,
                             const unsigned short* __restrict__ WeTs,
                             const float* __restrict__ att2pb,
                             const float* __restrict__ Wf,
                             float* __restrict__ att_part) {
  __shared__ unsigned short Bhs[3][16384];   // 3 x 32 KB, swizzled image

  const int bid = blockIdx.x;               // 0..195
  const int m0 = bid * 128;

  const int t = threadIdx.x;                // 0..511
  const int lane = t & 63, w = t >> 6;      // 8 waves
  const int wm = (w >> 2) * 64;             // 0 | 64
  const int wn = (w & 3) * 128;             // 0 | 128 | 256 | 384

  const int q = lane >> 4, fr = lane & 15;

  // A fragment-layout global base: lane covers row m0+wm+i*16+fr, k-chunk q
  const float* afr = enc + (size_t)(m0 + wm + fr) * E_ + q * 8;

  // B DMA: 4 x 16B per thread per K-tile (linear image copy)
  const int doff = t * 8;                   // shorts

  // B fragment read offsets (swizzled)
  const int fx = (fr & 7) << 3;
  int fb[8];
#pragma unroll
  for (int j = 0; j < 8; ++j) fb[j] = ((wn + j * 16 + fr) * 32 + q * 8) ^ fx;

  const f32x4 zero = {0.f, 0.f, 0.f, 0.f};
  f32x4 acc[4][8];
#pragma unroll
  for (int mi = 0; mi < 4; ++mi)
#pragma unroll
    for (int ni = 0; ni < 8; ++ni) acc[mi][ni] = zero;

  // rotating B buffers: bBc = compute (tile t), bB1 = t+1, bB2 = DMA tgt (t+2)
  unsigned short *bBc = &Bhs[0][0], *bB1 = &Bhs[1][0], *bB2 = &Bhs[2][0];

  f32x4 aC[8];   // A(t) f32 regs (4 frags x 8 floats)

  // ---- prologue: A(0) loads; B(0), B(1) DMAs
  {
#pragma unroll
    for (int i = 0; i < 4; ++i) {
      aC[2 * i]     = *(const f32x4*)(afr + (size_t)i * 16 * E_);
      aC[2 * i + 1] = *(const f32x4*)(afr + (size_t)i * 16 * E_ + 4);
    }
#pragma unroll
    for (int i = 0; i < 4; ++i)
      gl_lds16(WeTs + i * 4096 + doff, bBc + i * 4096 + doff);           // B(0)
#pragma unroll
    for (int i = 0; i < 4; ++i)
      gl_lds16(WeTs + 16384 + i * 4096 + doff, bB1 + i * 4096 + doff);   // B(1)
    WAIT_VM4();     // retires A(0) + B(0); leaves B(1) in flight
    __builtin_amdgcn_s_barrier();
  }

  for (int it = 0; it < 62; ++it) {
    // 1) cvt A(t) (regs loaded one iteration ago; compiler-counted wait)
    s16x8 fah[4];
#pragma unroll
    for (int i = 0; i < 4; ++i) fah[i] = cvt8s(aC[2 * i], aC[2 * i + 1]);

    // 2) issue A(t+1) loads + B(t+2) DMAs (12 VMEM ops this iter)
    {
      const int kof = (it + 1) * 32;
#pragma unroll
      for (int i = 0; i < 4; ++i) {
        aC[2 * i]     = *(const f32x4*)(afr + (size_t)i * 16 * E_ + kof);
        aC[2 * i + 1] = *(const f32x4*)(afr + (size_t)i * 16 * E_ + kof + 4);
      }
      const unsigned short* sb = WeTs + (size_t)(it + 2) * 16384;
#pragma unroll
      for (int i = 0; i < 4; ++i)
        gl_lds16(sb + i * 4096 + doff, bB2 + i * 4096 + doff);
    }

    // 3) B frags + MFMA
    s16x8 fbh[8];
#pragma unroll
    for (int j = 0; j < 8; ++j) fbh[j] = *(const s16x8*)(bBc + fb[j]);
    __builtin_amdgcn_s_setprio(1);
#pragma unroll
    for (int mi = 0; mi < 4; ++mi)
#pragma unroll
      for (int ni = 0; ni < 8; ++ni)
        acc[mi][ni] = __builtin_amdgcn_mfma_f32_16x16x32_bf16(fah[mi], fbh[ni], acc[mi][ni], 0, 0, 0);
    __builtin_amdgcn_s_setprio(0);

    // 4) counted drain: B(t+1) retired (12 newest = A(t+1)x8 + B(t+2)x4)
    WAIT_VM12();
    WAIT_LGKM0();
    __builtin_amdgcn_s_barrier();

    // 5) rotate B buffers
    unsigned short* tmp = bBc; bBc = bB1; bB1 = bB2; bB2 = tmp;
  }

  // ---- it = 62: cvt A(62), issue A(63) only; wait B(63)
  {
    s16x8 fah[4];
#pragma unroll
    for (int i = 0; i < 4; ++i) fah[i] = cvt8s(aC[2 * i], aC[2 * i + 1]);
    const int kof = 63 * 32;
#pragma unroll
    for (int i = 0; i < 4; ++i) {
      aC[2 * i]     = *(const f32x4*)(afr + (size_t)i * 16 * E_ + kof);
      aC[2 * i + 1] = *(const f32x4*)(afr + (size_t)i * 16 * E_ + kof + 4);
    }
    s16x8 fbh[8];
#pragma unroll
    for (int j = 0; j < 8; ++j) fbh[j] = *(const s16x8*)(bBc + fb[j]);
    __builtin_amdgcn_s_setprio(1);
#pragma unroll
    for (int mi = 0; mi < 4; ++mi)
#pragma unroll
      for (int ni = 0; ni < 8; ++ni)
        acc[mi][ni] = __builtin_amdgcn_mfma_f32_16x16x32_bf16(fah[mi], fbh[ni], acc[mi][ni], 0, 0, 0);
    __builtin_amdgcn_s_setprio(0);
    WAIT_VM8();     // retires B(63) (8 newest = A(63) loads)
    WAIT_LGKM0();
    __builtin_amdgcn_s_barrier();
    unsigned short* tmp = bBc; bBc = bB1; bB1 = bB2; bB2 = tmp;
  }

  // ---- it = 63: final tile
  {
    s16x8 fah[4];
#pragma unroll
    for (int i = 0; i < 4; ++i) fah[i] = cvt8s(aC[2 * i], aC[2 * i + 1]);
    s16x8 fbh[8];
#pragma unroll
    for (int j = 0; j < 8; ++j) fbh[j] = *(const s16x8*)(bBc + fb[j]);
#pragma unroll
    for (int mi = 0; mi < 4; ++mi)
#pragma unroll
      for (int ni = 0; ni < 8; ++ni)
        acc[mi][ni] = __builtin_amdgcn_mfma_f32_16x16x32_bf16(fah[mi], fbh[ni], acc[mi][ni], 0, 0, 0);
  }

  // epilogue: s = sum_col relu(acc + att2pb[b][col]) * Wf[col], 16-lane reduce
  // C/D layout: col = lane&15, row = (lane>>4)*4 + reg
  const int colL = wn + fr;
  float wfv[8];
#pragma unroll
  for (int ni = 0; ni < 8; ++ni) wfv[ni] = Wf[colL + ni * 16];
#pragma unroll
  for (int mi = 0; mi < 4; ++mi) {
    const int rowb = m0 + wm + mi * 16 + (q << 2);
#pragma unroll
    for (int r = 0; r < 4; ++r) {
      const int row = rowb + r;
      const int bb = row / P_;
      const float* a2 = att2pb + bb * A_ + colL;
      float s = 0.f;
#pragma unroll
      for (int ni = 0; ni < 8; ++ni)
        s += fmaxf(acc[mi][ni][r] + a2[ni * 16], 0.f) * wfv[ni];
#pragma unroll
      for (int off = 1; off < 16; off <<= 1) s += __shfl_xor(s, off);
      if (fr == 0) att_part[row * 4 + (w & 3)] = s;
    }
  }
}

// ---------------------------------------------------------------------------
// Kernel C: per (b, e-chunk): sum 4 partials -> softmax over P -> alpha,
// awe[b][e] = sum_p alpha[p] * enc[b][p][e].  grid = B*2, block 256.
// ---------------------------------------------------------------------------
__global__ void softmax_awe_kernel(const float* __restrict__ enc,
                                   const float* __restrict__ att_part,
                                   float* __restrict__ out) {
  const int bid = blockIdx.x;
  const int b = bid >> 1, ch = bid & 1;
  const int t = threadIdx.x;
  __shared__ float sm[256];
  __shared__ float alpha_s[P_];

  float av = -1e30f;
  if (t < P_) {
    const float* apt = att_part + (b * P_ + t) * 4;
    av = (apt[0] + apt[1]) + (apt[2] + apt[3]);
  }
  sm[t] = av;
  __syncthreads();
  for (int st = 128; st > 0; st >>= 1) {
    if (t < st) sm[t] = fmaxf(sm[t], sm[t + st]);
    __syncthreads();
  }
  const float mx = sm[0];
  __syncthreads();
  float ev = 0.f;
  if (t < P_) ev = __expf(av - mx);
  sm[t] = ev;
  __syncthreads();
  for (int st = 128; st > 0; st >>= 1) {
    if (t < st) sm[t] += sm[t + st];
    __syncthreads();
  }
  const float denom = sm[0];
  const float al = ev / denom;
  if (t < P_) {
    alpha_s[t] = al;
    if (ch == 0) out[B_ * E_ + b * P_ + t] = al;   // alpha output
  }
  __syncthreads();

  const int e0 = ch * 1024 + t * 4;
  const float* ebase = enc + (size_t)b * P_ * E_ + e0;
  f32x4 acc = {0.f, 0.f, 0.f, 0.f};
  for (int p = 0; p < P_; ++p) {
    const f32x4 v = *(const f32x4*)(ebase + (size_t)p * E_);
    const float a = alpha_s[p];
    acc.x += a * v.x; acc.y += a * v.y; acc.z += a * v.z; acc.w += a * v.w;
  }
  *(f32x4*)(out + b * E_ + e0) = acc;
}

// ---------------------------------------------------------------------------
extern "C" void kernel_launch(void* const* d_in, const int* in_sizes, int n_in,
                              void* d_out, int out_size, void* d_ws, size_t ws_size,
                              hipStream_t stream) {
  const float* enc = (const float*)d_in[0];
  const float* h   = (const float*)d_in[1];
  const float* We  = (const float*)d_in[2];
  const float* be  = (const float*)d_in[3];
  const float* Wd  = (const float*)d_in[4];
  const float* bd  = (const float*)d_in[5];
  const float* Wf  = (const float*)d_in[6];
  // d_in[7] = bf: constant shift before softmax -> cancels; unused.
  float* out = (float*)d_out;

  // workspace layout (~2.7 MB)
  float* att2pb = (float*)d_ws;                       // 128*512 f32
  float* att_part = att2pb + B_ * A_;                 // 25088*4 f32
  unsigned short* WeTs = (unsigned short*)(att_part + M_ * 4);  // 64*16384 u16

  we_conv_kernel<<<dim3(A_ / 32, E_ / 32), dim3(32, 32), 0, stream>>>(We, WeTs);
  att2_kernel<<<B_, 256, 0, stream>>>(h, Wd, bd, be, att2pb);
  score_kernel<<<M_ / 128, 512, 0, stream>>>(enc, WeTs, att2pb, Wf, att_part);
  softmax_awe_kernel<<<B_ * 2, 256, 0, stream>>>(enc, att_part, out);
}

// Round 10
// 139.174 us; speedup vs baseline: 1.4383x; 1.4383x over previous
//
#include <hip/hip_runtime.h>
#include <hip/hip_bf16.h>

typedef __attribute__((ext_vector_type(4))) float f32x4;
typedef __attribute__((ext_vector_type(4))) unsigned int u32x4;
typedef __attribute__((ext_vector_type(8))) short s16x8;

#define B_  128
#define P_  196
#define E_  2048
#define D_  512
#define A_  512
#define M_  (B_*P_)   // 25088

// global_load_lds: 16B per lane, dest = wave-uniform base + lane*16
typedef __attribute__((address_space(1))) const unsigned int gu32;
typedef __attribute__((address_space(3))) unsigned int lu32;
__device__ __forceinline__ void gl_lds16(const void* g, void* l) {
  __builtin_amdgcn_global_load_lds((gu32*)g, (lu32*)l, 16, 0, 0);
}

#define WAIT_VM6() asm volatile("s_waitcnt vmcnt(6)" ::: "memory")
#define WAIT_VM0() asm volatile("s_waitcnt vmcnt(0)" ::: "memory")
#define WAIT_LGKM0() asm volatile("s_waitcnt lgkmcnt(0)" ::: "memory")

// ---------------------------------------------------------------------------
// Kernel W: transpose + rne-bf16 + PRE-SWIZZLED TILED store:
// WeTs[kt*16384 + ((a*32 + c8*8) ^ ((a&7)<<3)) + j] == exact 32KB LDS image
// of K-tile kt (a = n-row 0..511, c8 = (e&31)>>3, j = e&7).
// ---------------------------------------------------------------------------
__global__ void we_conv_kernel(const float* __restrict__ We,
                               unsigned short* __restrict__ WeTs) {
  __shared__ float tile[32][33];
  const int tx = threadIdx.x, ty = threadIdx.y;
  const int a0 = blockIdx.x * 32, e0 = blockIdx.y * 32;
  tile[ty][tx] = We[(e0 + ty) * A_ + a0 + tx];
  __syncthreads();
  const float v = tile[tx][ty];              // = We[e0+tx][a0+ty]
  const unsigned int u = __float_as_uint(v);
  const unsigned short r = (unsigned short)((u + 0x7fffu + ((u >> 16) & 1u)) >> 16);
  const int a = a0 + ty;                     // n-row 0..511
  const int kt = blockIdx.y;                 // e-tile
  const int c8 = tx >> 3, j = tx & 7;
  const int dest = ((a * 32 + c8 * 8) ^ ((a & 7) << 3)) + j;
  WeTs[kt * 16384 + dest] = r;
}

// ---------------------------------------------------------------------------
// Kernel A: att2pb[b][a] = decoder_hidden[b] @ Wd + bd[a] + be[a]  (fp32)
// ---------------------------------------------------------------------------
__global__ void att2_kernel(const float* __restrict__ h, const float* __restrict__ Wd,
                            const float* __restrict__ bd, const float* __restrict__ be,
                            float* __restrict__ att2pb) {
  const int b = blockIdx.x;
  const int t = threadIdx.x;  // 256
  __shared__ float hs[D_];
  hs[t] = h[b * D_ + t];
  hs[t + 256] = h[b * D_ + t + 256];
  __syncthreads();
  float a0 = 0.f, a1 = 0.f;
  for (int d = 0; d < D_; ++d) {
    const float hv = hs[d];
    a0 = fmaf(hv, Wd[d * A_ + t], a0);
    a1 = fmaf(hv, Wd[d * A_ + t + 256], a1);
  }
  att2pb[b * A_ + t] = a0 + bd[t] + be[t];
  att2pb[b * A_ + t + 256] = a1 + bd[t + 256] + be[t + 256];
}

// ---------------------------------------------------------------------------
__device__ inline unsigned pk2(float a, float b) {
  union { __hip_bfloat162 h; unsigned u; } cv;
  cv.h = __float22bfloat162_rn(make_float2(a, b));
  return cv.u;
}
__device__ inline u32x4 cvt8(const f32x4 lo, const f32x4 hi) {
  u32x4 r;
  r[0] = pk2(lo[0], lo[1]);
  r[1] = pk2(lo[2], lo[3]);
  r[2] = pk2(hi[0], hi[1]);
  r[3] = pk2(hi[2], hi[3]);
  return r;
}

// ---------------------------------------------------------------------------
// Kernel B v9: R6 structure (128m x 512n strip, 8 waves, K=32, triple-buffer,
// depth-2 prefetch, counted vmcnt + raw barrier) + m201-style 4-PHASE
// INTRA-TILE INTERLEAVE: per K-tile, the 32-MFMA cluster splits into 4
// quadrant phases {ds_read quad; 1 DMA chunk; bar; lgkm(0); prio1; 8 MFMA;
// prio0; bar} so SIMD-mate waves de-phase (reads overlap MFMA).
// Intra-tile barriers are scheduling-only; correctness sync (vmcnt(6)+
// lgkm(0)+barrier once per tile) is exactly R6's proven discipline.
// ---------------------------------------------------------------------------
__launch_bounds__(512, 2)
__global__ void score_kernel(const float* __restrict__ enc,
                             const unsigned short* __restrict__ WeTs,
                             const float* __restrict__ att2pb,
                             const float* __restrict__ Wf,
                             float* __restrict__ att_part) {
  __shared__ unsigned short Bh[3][512 * 32];   // 3 x 32 KB, swizzled image
  __shared__ unsigned short Ahs[3][128 * 32];  // 3 x  8 KB, swizzled image

  const int bid = blockIdx.x;               // 0..195
  const int m0 = bid * 128;

  const int t = threadIdx.x;                // 0..511
  const int lane = t & 63, w = t >> 6;      // 8 waves
  const int wm = (w >> 2) * 64;             // 0 | 64
  const int wn = (w & 3) * 128;             // 0 | 128 | 256 | 384

  // A staging: row ar = t>>2, 8 f32 at chunk ac = t&3
  const int ar = t >> 2, ac = t & 3;
  const float* aptr = enc + (size_t)(m0 + ar) * E_ + ac * 8;
  const int awz = (ar * 32 + ac * 8) ^ ((ar & 7) << 3);
  const int doff = t * 8;                   // DMA offset in shorts

  // fragment read offsets
  const int q = lane >> 4, fr = lane & 15;
  const int fx = (fr & 7) << 3;
  int fa[4], fb[8];
#pragma unroll
  for (int i = 0; i < 4; ++i) fa[i] = ((wm + i * 16 + fr) * 32 + q * 8) ^ fx;
#pragma unroll
  for (int j = 0; j < 8; ++j) fb[j] = ((wn + j * 16 + fr) * 32 + q * 8) ^ fx;

  const f32x4 zero = {0.f, 0.f, 0.f, 0.f};
  f32x4 acc[4][8];
#pragma unroll
  for (int mi = 0; mi < 4; ++mi)
#pragma unroll
    for (int ni = 0; ni < 8; ++ni) acc[mi][ni] = zero;

  // rotating buffers: *_c = compute (tile t), *_1 = t+1, *_2 = DMA tgt (t+2)
  unsigned short *bAc = &Ahs[0][0], *bA1 = &Ahs[1][0], *bA2 = &Ahs[2][0];
  unsigned short *bBc = &Bh[0][0],  *bB1 = &Bh[1][0],  *bB2 = &Bh[2][0];

  f32x4 aC0, aC1, aN0, aN1;

  // ---- prologue: stage tiles 0 and 1 (VMEM order: A0 x2, B0 x4, A1 x2, B1 x4)
  {
    aC0 = *(const f32x4*)(aptr);              // A(0)
    aC1 = *(const f32x4*)(aptr + 4);
#pragma unroll
    for (int i = 0; i < 4; ++i)
      gl_lds16(WeTs + i * 4096 + doff, bBc + i * 4096 + doff);   // B(0)
    aN0 = *(const f32x4*)(aptr + 32);         // A(1)
    aN1 = *(const f32x4*)(aptr + 36);
#pragma unroll
    for (int i = 0; i < 4; ++i)
      gl_lds16(WeTs + 16384 + i * 4096 + doff, bB1 + i * 4096 + doff);  // B(1)
    const u32x4 av = cvt8(aC0, aC1);          // waits A(0) only (compiler-counted)
    *(u32x4*)(bAc + awz) = av;
    aC0 = aN0; aC1 = aN1;
    WAIT_VM6();     // B(0) retired (newest 6 = A(1)x2 + B(1)x4)
    WAIT_LGKM0();
    __builtin_amdgcn_s_barrier();
  }

  for (int it = 0; it < 62; ++it) {
    const unsigned short* sb = WeTs + (size_t)(it + 2) * 16384;
    const int kof = (it + 2) * 32;
    s16x8 fah[4], fbh[8];

    // ================= phase 0: A-frags + B quad0; DMA chunk0; A(t+2) loads
    fah[0] = *(const s16x8*)(bAc + fa[0]);
    fah[1] = *(const s16x8*)(bAc + fa[1]);
    fah[2] = *(const s16x8*)(bAc + fa[2]);
    fah[3] = *(const s16x8*)(bAc + fa[3]);
    fbh[0] = *(const s16x8*)(bBc + fb[0]);
    fbh[1] = *(const s16x8*)(bBc + fb[1]);
    gl_lds16(sb + doff, bB2 + doff);
    aN0 = *(const f32x4*)(aptr + kof);
    aN1 = *(const f32x4*)(aptr + kof + 4);
    __builtin_amdgcn_s_barrier();
    WAIT_LGKM0();
    __builtin_amdgcn_s_setprio(1);
#pragma unroll
    for (int mi = 0; mi < 4; ++mi) {
      acc[mi][0] = __builtin_amdgcn_mfma_f32_16x16x32_bf16(fah[mi], fbh[0], acc[mi][0], 0, 0, 0);
      acc[mi][1] = __builtin_amdgcn_mfma_f32_16x16x32_bf16(fah[mi], fbh[1], acc[mi][1], 0, 0, 0);
    }
    __builtin_amdgcn_s_setprio(0);
    __builtin_amdgcn_s_barrier();

    // ================= phase 1: B quad1; DMA chunk1
    fbh[2] = *(const s16x8*)(bBc + fb[2]);
    fbh[3] = *(const s16x8*)(bBc + fb[3]);
    gl_lds16(sb + 4096 + doff, bB2 + 4096 + doff);
    __builtin_amdgcn_s_barrier();
    WAIT_LGKM0();
    __builtin_amdgcn_s_setprio(1);
#pragma unroll
    for (int mi = 0; mi < 4; ++mi) {
      acc[mi][2] = __builtin_amdgcn_mfma_f32_16x16x32_bf16(fah[mi], fbh[2], acc[mi][2], 0, 0, 0);
      acc[mi][3] = __builtin_amdgcn_mfma_f32_16x16x32_bf16(fah[mi], fbh[3], acc[mi][3], 0, 0, 0);
    }
    __builtin_amdgcn_s_setprio(0);
    __builtin_amdgcn_s_barrier();

    // ================= phase 2: B quad2; DMA chunk2
    fbh[4] = *(const s16x8*)(bBc + fb[4]);
    fbh[5] = *(const s16x8*)(bBc + fb[5]);
    gl_lds16(sb + 8192 + doff, bB2 + 8192 + doff);
    __builtin_amdgcn_s_barrier();
    WAIT_LGKM0();
    __builtin_amdgcn_s_setprio(1);
#pragma unroll
    for (int mi = 0; mi < 4; ++mi) {
      acc[mi][4] = __builtin_amdgcn_mfma_f32_16x16x32_bf16(fah[mi], fbh[4], acc[mi][4], 0, 0, 0);
      acc[mi][5] = __builtin_amdgcn_mfma_f32_16x16x32_bf16(fah[mi], fbh[5], acc[mi][5], 0, 0, 0);
    }
    __builtin_amdgcn_s_setprio(0);
    __builtin_amdgcn_s_barrier();

    // ================= phase 3: B quad3; DMA chunk3; cvt+write A(t+1);
    // correctness sync: lgkm(0) + vmcnt(6) + barrier (R6 discipline)
    fbh[6] = *(const s16x8*)(bBc + fb[6]);
    fbh[7] = *(const s16x8*)(bBc + fb[7]);
    gl_lds16(sb + 12288 + doff, bB2 + 12288 + doff);
    {
      const u32x4 av = cvt8(aC0, aC1);   // A(t+1) regs, loaded last iter
      *(u32x4*)(bA1 + awz) = av;
    }
    aC0 = aN0; aC1 = aN1;
    __builtin_amdgcn_s_barrier();
    WAIT_LGKM0();
    __builtin_amdgcn_s_setprio(1);
#pragma unroll
    for (int mi = 0; mi < 4; ++mi) {
      acc[mi][6] = __builtin_amdgcn_mfma_f32_16x16x32_bf16(fah[mi], fbh[6], acc[mi][6], 0, 0, 0);
      acc[mi][7] = __builtin_amdgcn_mfma_f32_16x16x32_bf16(fah[mi], fbh[7], acc[mi][7], 0, 0, 0);
    }
    __builtin_amdgcn_s_setprio(0);
    WAIT_VM6();     // retires B(t+1)+A(t+1) (newest 6 = this iter's issues)
    __builtin_amdgcn_s_barrier();

    // rotate buffers
    unsigned short* tmp;
    tmp = bAc; bAc = bA1; bA1 = bA2; bA2 = tmp;
    tmp = bBc; bBc = bB1; bB1 = bB2; bB2 = tmp;
  }

  // ---- it = 62: compute tile 62 (simple), cvt+write A(63), full drain
  {
    s16x8 fah[4], fbh[8];
#pragma unroll
    for (int j = 0; j < 8; ++j) fbh[j] = *(const s16x8*)(bBc + fb[j]);
#pragma unroll
    for (int i = 0; i < 4; ++i) fah[i] = *(const s16x8*)(bAc + fa[i]);
    __builtin_amdgcn_s_setprio(1);
#pragma unroll
    for (int mi = 0; mi < 4; ++mi)
#pragma unroll
      for (int ni = 0; ni < 8; ++ni)
        acc[mi][ni] = __builtin_amdgcn_mfma_f32_16x16x32_bf16(fah[mi], fbh[ni], acc[mi][ni], 0, 0, 0);
    __builtin_amdgcn_s_setprio(0);
    const u32x4 av = cvt8(aC0, aC1);          // A(63)
    *(u32x4*)(bA1 + awz) = av;
    WAIT_VM0();     // B(63) retired
    WAIT_LGKM0();
    __builtin_amdgcn_s_barrier();
  }

  // ---- it = 63: compute tile 63 from bA1/bB1
  {
    s16x8 fah[4], fbh[8];
#pragma unroll
    for (int j = 0; j < 8; ++j) fbh[j] = *(const s16x8*)(bB1 + fb[j]);
#pragma unroll
    for (int i = 0; i < 4; ++i) fah[i] = *(const s16x8*)(bA1 + fa[i]);
#pragma unroll
    for (int mi = 0; mi < 4; ++mi)
#pragma unroll
      for (int ni = 0; ni < 8; ++ni)
        acc[mi][ni] = __builtin_amdgcn_mfma_f32_16x16x32_bf16(fah[mi], fbh[ni], acc[mi][ni], 0, 0, 0);
  }

  // epilogue: s = sum_col relu(acc + att2pb[b][col]) * Wf[col], 16-lane reduce
  // C/D layout: col = lane&15, row = (lane>>4)*4 + reg
  const int colL = wn + fr;
  float wfv[8];
#pragma unroll
  for (int ni = 0; ni < 8; ++ni) wfv[ni] = Wf[colL + ni * 16];
#pragma unroll
  for (int mi = 0; mi < 4; ++mi) {
    const int rowb = m0 + wm + mi * 16 + (q << 2);
#pragma unroll
    for (int r = 0; r < 4; ++r) {
      const int row = rowb + r;
      const int bb = row / P_;
      const float* a2 = att2pb + bb * A_ + colL;
      float s = 0.f;
#pragma unroll
      for (int ni = 0; ni < 8; ++ni)
        s += fmaxf(acc[mi][ni][r] + a2[ni * 16], 0.f) * wfv[ni];
#pragma unroll
      for (int off = 1; off < 16; off <<= 1) s += __shfl_xor(s, off);
      if (fr == 0) att_part[row * 4 + (w & 3)] = s;
    }
  }
}

// ---------------------------------------------------------------------------
// Kernel C: per (b, e-chunk): sum 4 partials -> softmax over P -> alpha,
// awe[b][e] = sum_p alpha[p] * enc[b][p][e].  grid = B*2, block 256.
// ---------------------------------------------------------------------------
__global__ void softmax_awe_kernel(const float* __restrict__ enc,
                                   const float* __restrict__ att_part,
                                   float* __restrict__ out) {
  const int bid = blockIdx.x;
  const int b = bid >> 1, ch = bid & 1;
  const int t = threadIdx.x;
  __shared__ float sm[256];
  __shared__ float alpha_s[P_];

  float av = -1e30f;
  if (t < P_) {
    const float* apt = att_part + (b * P_ + t) * 4;
    av = (apt[0] + apt[1]) + (apt[2] + apt[3]);
  }
  sm[t] = av;
  __syncthreads();
  for (int st = 128; st > 0; st >>= 1) {
    if (t < st) sm[t] = fmaxf(sm[t], sm[t + st]);
    __syncthreads();
  }
  const float mx = sm[0];
  __syncthreads();
  float ev = 0.f;
  if (t < P_) ev = __expf(av - mx);
  sm[t] = ev;
  __syncthreads();
  for (int st = 128; st > 0; st >>= 1) {
    if (t < st) sm[t] += sm[t + st];
    __syncthreads();
  }
  const float denom = sm[0];
  const float al = ev / denom;
  if (t < P_) {
    alpha_s[t] = al;
    if (ch == 0) out[B_ * E_ + b * P_ + t] = al;   // alpha output
  }
  __syncthreads();

  const int e0 = ch * 1024 + t * 4;
  const float* ebase = enc + (size_t)b * P_ * E_ + e0;
  f32x4 acc = {0.f, 0.f, 0.f, 0.f};
  for (int p = 0; p < P_; ++p) {
    const f32x4 v = *(const f32x4*)(ebase + (size_t)p * E_);
    const float a = alpha_s[p];
    acc.x += a * v.x; acc.y += a * v.y; acc.z += a * v.z; acc.w += a * v.w;
  }
  *(f32x4*)(out + b * E_ + e0) = acc;
}

// ---------------------------------------------------------------------------
extern "C" void kernel_launch(void* const* d_in, const int* in_sizes, int n_in,
                              void* d_out, int out_size, void* d_ws, size_t ws_size,
                              hipStream_t stream) {
  const float* enc = (const float*)d_in[0];
  const float* h   = (const float*)d_in[1];
  const float* We  = (const float*)d_in[2];
  const float* be  = (const float*)d_in[3];
  const float* Wd  = (const float*)d_in[4];
  const float* bd  = (const float*)d_in[5];
  const float* Wf  = (const float*)d_in[6];
  // d_in[7] = bf: constant shift before softmax -> cancels; unused.
  float* out = (float*)d_out;

  // workspace layout (~2.7 MB)
  float* att2pb = (float*)d_ws;                       // 128*512 f32
  float* att_part = att2pb + B_ * A_;                 // 25088*4 f32
  unsigned short* WeTs = (unsigned short*)(att_part + M_ * 4);  // 64*16384 u16

  we_conv_kernel<<<dim3(A_ / 32, E_ / 32), dim3(32, 32), 0, stream>>>(We, WeTs);
  att2_kernel<<<B_, 256, 0, stream>>>(h, Wd, bd, be, att2pb);
  score_kernel<<<M_ / 128, 512, 0, stream>>>(enc, WeTs, att2pb, Wf, att_part);
  softmax_awe_kernel<<<B_ * 2, 256, 0, stream>>>(enc, att_part, out);
}

// Round 11
// 130.219 us; speedup vs baseline: 1.5372x; 1.0688x over previous
//
#include <hip/hip_runtime.h>
#include <hip/hip_bf16.h>

typedef __attribute__((ext_vector_type(2))) unsigned int u32x2;
typedef __attribute__((ext_vector_type(4))) float f32x4;
typedef __attribute__((ext_vector_type(4))) unsigned int u32x4;
typedef __attribute__((ext_vector_type(8))) short s16x8;

#define B_  128
#define P_  196
#define E_  2048
#define D_  512
#define A_  512
#define M_  (B_*P_)   // 25088

// global_load_lds: 16B per lane, dest = wave-uniform base + lane*16
typedef __attribute__((address_space(1))) const unsigned int gu32;
typedef __attribute__((address_space(3))) unsigned int lu32;
__device__ __forceinline__ void gl_lds16(const void* g, void* l) {
  __builtin_amdgcn_global_load_lds((gu32*)g, (lu32*)l, 16, 0, 0);
}

#define WAIT_VM3() asm volatile("s_waitcnt vmcnt(3)" ::: "memory")
#define WAIT_VM0() asm volatile("s_waitcnt vmcnt(0)" ::: "memory")
#define WAIT_LGKM0() asm volatile("s_waitcnt lgkmcnt(0)" ::: "memory")

// ---------------------------------------------------------------------------
// Kernel W: transpose + rne-bf16 + PRE-SWIZZLED TILED store:
// WeTs[kt*16384 + ((a*32 + c8*8) ^ ((a&7)<<3)) + j] == exact 32KB LDS image
// of K-tile kt (a = n-row 0..511, c8 = (e&31)>>3, j = e&7).
// ---------------------------------------------------------------------------
__global__ void we_conv_kernel(const float* __restrict__ We,
                               unsigned short* __restrict__ WeTs) {
  __shared__ float tile[32][33];
  const int tx = threadIdx.x, ty = threadIdx.y;
  const int a0 = blockIdx.x * 32, e0 = blockIdx.y * 32;
  tile[ty][tx] = We[(e0 + ty) * A_ + a0 + tx];
  __syncthreads();
  const float v = tile[tx][ty];              // = We[e0+tx][a0+ty]
  const unsigned int u = __float_as_uint(v);
  const unsigned short r = (unsigned short)((u + 0x7fffu + ((u >> 16) & 1u)) >> 16);
  const int a = a0 + ty;                     // n-row 0..511
  const int kt = blockIdx.y;                 // e-tile
  const int c8 = tx >> 3, j = tx & 7;
  const int dest = ((a * 32 + c8 * 8) ^ ((a & 7) << 3)) + j;
  WeTs[kt * 16384 + dest] = r;
}

// ---------------------------------------------------------------------------
// Kernel A: att2pb[b][a] = decoder_hidden[b] @ Wd + bd[a] + be[a]  (fp32)
// ---------------------------------------------------------------------------
__global__ void att2_kernel(const float* __restrict__ h, const float* __restrict__ Wd,
                            const float* __restrict__ bd, const float* __restrict__ be,
                            float* __restrict__ att2pb) {
  const int b = blockIdx.x;
  const int t = threadIdx.x;  // 256
  __shared__ float hs[D_];
  hs[t] = h[b * D_ + t];
  hs[t + 256] = h[b * D_ + t + 256];
  __syncthreads();
  float a0 = 0.f, a1 = 0.f;
  for (int d = 0; d < D_; ++d) {
    const float hv = hs[d];
    a0 = fmaf(hv, Wd[d * A_ + t], a0);
    a1 = fmaf(hv, Wd[d * A_ + t + 256], a1);
  }
  att2pb[b * A_ + t] = a0 + bd[t] + be[t];
  att2pb[b * A_ + t + 256] = a1 + bd[t + 256] + be[t + 256];
}

// ---------------------------------------------------------------------------
__device__ inline unsigned pk2(float a, float b) {
  union { __hip_bfloat162 h; unsigned u; } cv;
  cv.h = __float22bfloat162_rn(make_float2(a, b));
  return cv.u;
}

// ---------------------------------------------------------------------------
// Kernel B v10: R6 pipeline at 16 waves (1024 thr), wave tile 32x128 (4m x 4n).
// Triple-buffered, depth-2 prefetch, counted vmcnt(3) + raw barrier.
// A: 1 f32x4 load + cvt + ds_write_b64 per thread. B: 2 gl_lds16 per thread.
// B-frags processed in 2 halves of 4 to stay <=128 VGPR (16 waves/CU).
// ---------------------------------------------------------------------------
__launch_bounds__(1024, 4)
__global__ void score_kernel(const float* __restrict__ enc,
                             const unsigned short* __restrict__ WeTs,
                             const float* __restrict__ att2pb,
                             const float* __restrict__ Wf,
                             float* __restrict__ att_part) {
  __shared__ unsigned short Bh[3][512 * 32];   // 3 x 32 KB, swizzled image
  __shared__ unsigned short Ahs[3][128 * 32];  // 3 x  8 KB, swizzled image

  const int bid = blockIdx.x;               // 0..195
  const int m0 = bid * 128;

  const int t = threadIdx.x;                // 0..1023
  const int lane = t & 63, w = t >> 6;      // 16 waves
  const int wm = (w >> 2) * 32;             // 0 | 32 | 64 | 96
  const int wn = (w & 3) * 128;             // 0 | 128 | 256 | 384

  // A staging: row r = t>>3 (0..127), 4 f32 at chunk c4 = t&7 -> 8B LDS write
  const int ar = t >> 3, ac4 = t & 7;
  const float* aptr = enc + (size_t)(m0 + ar) * E_ + ac4 * 4;
  const int awz = (ar * 32 + ac4 * 4) ^ ((ar & 7) << 3);   // shorts, 8B-aligned

  // B DMA: 2 x 16B per thread (linear image copy)
  const int doff = t * 8;                   // shorts; chunk i at +i*8192

  // fragment read offsets
  const int q = lane >> 4, fr = lane & 15;
  const int fx = (fr & 7) << 3;
  int fa[2], fb[8];
#pragma unroll
  for (int i = 0; i < 2; ++i) fa[i] = ((wm + i * 16 + fr) * 32 + q * 8) ^ fx;
#pragma unroll
  for (int j = 0; j < 8; ++j) fb[j] = ((wn + j * 16 + fr) * 32 + q * 8) ^ fx;

  const f32x4 zero = {0.f, 0.f, 0.f, 0.f};
  f32x4 acc[2][8];
#pragma unroll
  for (int mi = 0; mi < 2; ++mi)
#pragma unroll
    for (int ni = 0; ni < 8; ++ni) acc[mi][ni] = zero;

  // rotating buffers: *_c = compute (tile t), *_1 = t+1, *_2 = DMA tgt (t+2)
  unsigned short *bAc = &Ahs[0][0], *bA1 = &Ahs[1][0], *bA2 = &Ahs[2][0];
  unsigned short *bBc = &Bh[0][0],  *bB1 = &Bh[1][0],  *bB2 = &Bh[2][0];

  f32x4 aC, aN;   // A regs: aC = tile t+1 (cvt at end of iter t), aN = t+2

  // ---- prologue: stage tiles 0 and 1 (order: A0, B0 x2, A1, B1 x2)
  {
    aC = *(const f32x4*)(aptr);                           // A(0)
    gl_lds16(WeTs + doff, bBc + doff);                    // B(0)
    gl_lds16(WeTs + 8192 + doff, bBc + 8192 + doff);
    aN = *(const f32x4*)(aptr + 32);                      // A(1)
    gl_lds16(WeTs + 16384 + doff, bB1 + doff);            // B(1)
    gl_lds16(WeTs + 16384 + 8192 + doff, bB1 + 8192 + doff);
    u32x2 av; av[0] = pk2(aC[0], aC[1]); av[1] = pk2(aC[2], aC[3]);
    *(u32x2*)(bAc + awz) = av;                            // A(0) -> LDS
    aC = aN;
    WAIT_VM3();     // retires B(0); leaves A(1)+B(1)x2 in flight
    WAIT_LGKM0();
    __builtin_amdgcn_s_barrier();
  }

  for (int it = 0; it < 62; ++it) {
    // 1) issue stage(t+2): 1 A-load + 2 B-DMAs  (3 VMEM ops this iter)
    const int kof = (it + 2) * 32;
    aN = *(const f32x4*)(aptr + kof);
    const unsigned short* sb = WeTs + (size_t)(it + 2) * 16384;
    gl_lds16(sb + doff, bB2 + doff);
    gl_lds16(sb + 8192 + doff, bB2 + 8192 + doff);

    // 2) compute buffer t (B in two halves of 4 frags: register pressure)
    s16x8 fah[2], fbh[4];
    fah[0] = *(const s16x8*)(bAc + fa[0]);
    fah[1] = *(const s16x8*)(bAc + fa[1]);
#pragma unroll
    for (int j = 0; j < 4; ++j) fbh[j] = *(const s16x8*)(bBc + fb[j]);
    __builtin_amdgcn_s_setprio(1);
#pragma unroll
    for (int mi = 0; mi < 2; ++mi)
#pragma unroll
      for (int ni = 0; ni < 4; ++ni)
        acc[mi][ni] = __builtin_amdgcn_mfma_f32_16x16x32_bf16(fah[mi], fbh[ni], acc[mi][ni], 0, 0, 0);
    __builtin_amdgcn_s_setprio(0);
#pragma unroll
    for (int j = 0; j < 4; ++j) fbh[j] = *(const s16x8*)(bBc + fb[4 + j]);
    __builtin_amdgcn_s_setprio(1);
#pragma unroll
    for (int mi = 0; mi < 2; ++mi)
#pragma unroll
      for (int ni = 0; ni < 4; ++ni)
        acc[mi][4 + ni] = __builtin_amdgcn_mfma_f32_16x16x32_bf16(fah[mi], fbh[ni], acc[mi][4 + ni], 0, 0, 0);
    __builtin_amdgcn_s_setprio(0);

    // 3) cvt + write A(t+1) (aC regs issued last iter; compiler-counted wait)
    {
      u32x2 av; av[0] = pk2(aC[0], aC[1]); av[1] = pk2(aC[2], aC[3]);
      *(u32x2*)(bA1 + awz) = av;
    }
    aC = aN;

    // 4) counted drain: this iter's 3 stay in flight; tile t+1 fully resident
    WAIT_VM3();
    WAIT_LGKM0();
    __builtin_amdgcn_s_barrier();

    // 5) rotate
    unsigned short* tmp;
    tmp = bAc; bAc = bA1; bA1 = bA2; bA2 = tmp;
    tmp = bBc; bBc = bB1; bB1 = bB2; bB2 = tmp;
  }

  // ---- it = 62: compute tile 62, cvt+write A(63), full drain
  {
    s16x8 fah[2], fbh[4];
    fah[0] = *(const s16x8*)(bAc + fa[0]);
    fah[1] = *(const s16x8*)(bAc + fa[1]);
#pragma unroll
    for (int j = 0; j < 4; ++j) fbh[j] = *(const s16x8*)(bBc + fb[j]);
#pragma unroll
    for (int mi = 0; mi < 2; ++mi)
#pragma unroll
      for (int ni = 0; ni < 4; ++ni)
        acc[mi][ni] = __builtin_amdgcn_mfma_f32_16x16x32_bf16(fah[mi], fbh[ni], acc[mi][ni], 0, 0, 0);
#pragma unroll
    for (int j = 0; j < 4; ++j) fbh[j] = *(const s16x8*)(bBc + fb[4 + j]);
#pragma unroll
    for (int mi = 0; mi < 2; ++mi)
#pragma unroll
      for (int ni = 0; ni < 4; ++ni)
        acc[mi][4 + ni] = __builtin_amdgcn_mfma_f32_16x16x32_bf16(fah[mi], fbh[ni], acc[mi][4 + ni], 0, 0, 0);
    u32x2 av; av[0] = pk2(aC[0], aC[1]); av[1] = pk2(aC[2], aC[3]);
    *(u32x2*)(bA1 + awz) = av;                            // A(63)
    WAIT_VM0();     // B(63) retired
    WAIT_LGKM0();
    __builtin_amdgcn_s_barrier();
  }

  // ---- it = 63: compute tile 63 from bA1/bB1
  {
    s16x8 fah[2], fbh[4];
    fah[0] = *(const s16x8*)(bA1 + fa[0]);
    fah[1] = *(const s16x8*)(bA1 + fa[1]);
#pragma unroll
    for (int j = 0; j < 4; ++j) fbh[j] = *(const s16x8*)(bB1 + fb[j]);
#pragma unroll
    for (int mi = 0; mi < 2; ++mi)
#pragma unroll
      for (int ni = 0; ni < 4; ++ni)
        acc[mi][ni] = __builtin_amdgcn_mfma_f32_16x16x32_bf16(fah[mi], fbh[ni], acc[mi][ni], 0, 0, 0);
#pragma unroll
    for (int j = 0; j < 4; ++j) fbh[j] = *(const s16x8*)(bB1 + fb[4 + j]);
#pragma unroll
    for (int mi = 0; mi < 2; ++mi)
#pragma unroll
      for (int ni = 0; ni < 4; ++ni)
        acc[mi][4 + ni] = __builtin_amdgcn_mfma_f32_16x16x32_bf16(fah[mi], fbh[ni], acc[mi][4 + ni], 0, 0, 0);
  }

  // epilogue: s = sum_col relu(acc + att2pb[b][col]) * Wf[col], 16-lane reduce
  // C/D layout: col = lane&15, row = (lane>>4)*4 + reg
  const int colL = wn + fr;
  float wfv[8];
#pragma unroll
  for (int ni = 0; ni < 8; ++ni) wfv[ni] = Wf[colL + ni * 16];
#pragma unroll
  for (int mi = 0; mi < 2; ++mi) {
    const int rowb = m0 + wm + mi * 16 + (q << 2);
#pragma unroll
    for (int r = 0; r < 4; ++r) {
      const int row = rowb + r;
      const int bb = row / P_;
      const float* a2 = att2pb + bb * A_ + colL;
      float s = 0.f;
#pragma unroll
      for (int ni = 0; ni < 8; ++ni)
        s += fmaxf(acc[mi][ni][r] + a2[ni * 16], 0.f) * wfv[ni];
#pragma unroll
      for (int off = 1; off < 16; off <<= 1) s += __shfl_xor(s, off);
      if (fr == 0) att_part[row * 4 + (w & 3)] = s;
    }
  }
}

// ---------------------------------------------------------------------------
// Kernel C: per (b, e-chunk): sum 4 partials -> softmax over P -> alpha,
// awe[b][e] = sum_p alpha[p] * enc[b][p][e].  grid = B*2, block 256.
// ---------------------------------------------------------------------------
__global__ void softmax_awe_kernel(const float* __restrict__ enc,
                                   const float* __restrict__ att_part,
                                   float* __restrict__ out) {
  const int bid = blockIdx.x;
  const int b = bid >> 1, ch = bid & 1;
  const int t = threadIdx.x;
  __shared__ float sm[256];
  __shared__ float alpha_s[P_];

  float av = -1e30f;
  if (t < P_) {
    const float* apt = att_part + (b * P_ + t) * 4;
    av = (apt[0] + apt[1]) + (apt[2] + apt[3]);
  }
  sm[t] = av;
  __syncthreads();
  for (int st = 128; st > 0; st >>= 1) {
    if (t < st) sm[t] = fmaxf(sm[t], sm[t + st]);
    __syncthreads();
  }
  const float mx = sm[0];
  __syncthreads();
  float ev = 0.f;
  if (t < P_) ev = __expf(av - mx);
  sm[t] = ev;
  __syncthreads();
  for (int st = 128; st > 0; st >>= 1) {
    if (t < st) sm[t] += sm[t + st];
    __syncthreads();
  }
  const float denom = sm[0];
  const float al = ev / denom;
  if (t < P_) {
    alpha_s[t] = al;
    if (ch == 0) out[B_ * E_ + b * P_ + t] = al;   // alpha output
  }
  __syncthreads();

  const int e0 = ch * 1024 + t * 4;
  const float* ebase = enc + (size_t)b * P_ * E_ + e0;
  f32x4 acc = {0.f, 0.f, 0.f, 0.f};
  for (int p = 0; p < P_; ++p) {
    const f32x4 v = *(const f32x4*)(ebase + (size_t)p * E_);
    const float a = alpha_s[p];
    acc.x += a * v.x; acc.y += a * v.y; acc.z += a * v.z; acc.w += a * v.w;
  }
  *(f32x4*)(out + b * E_ + e0) = acc;
}

// ---------------------------------------------------------------------------
extern "C" void kernel_launch(void* const* d_in, const int* in_sizes, int n_in,
                              void* d_out, int out_size, void* d_ws, size_t ws_size,
                              hipStream_t stream) {
  const float* enc = (const float*)d_in[0];
  const float* h   = (const float*)d_in[1];
  const float* We  = (const float*)d_in[2];
  const float* be  = (const float*)d_in[3];
  const float* Wd  = (const float*)d_in[4];
  const float* bd  = (const float*)d_in[5];
  const float* Wf  = (const float*)d_in[6];
  // d_in[7] = bf: constant shift before softmax -> cancels; unused.
  float* out = (float*)d_out;

  // workspace layout (~2.7 MB)
  float* att2pb = (float*)d_ws;                       // 128*512 f32
  float* att_part = att2pb + B_ * A_;                 // 25088*4 f32
  unsigned short* WeTs = (unsigned short*)(att_part + M_ * 4);  // 64*16384 u16

  we_conv_kernel<<<dim3(A_ / 32, E_ / 32), dim3(32, 32), 0, stream>>>(We, WeTs);
  att2_kernel<<<B_, 256, 0, stream>>>(h, Wd, bd, be, att2pb);
  score_kernel<<<M_ / 128, 1024, 0, stream>>>(enc, WeTs, att2pb, Wf, att_part);
  softmax_awe_kernel<<<B_ * 2, 256, 0, stream>>>(enc, att_part, out);
}